// Round 7
// baseline (308.998 us; speedup 1.0000x reference)
//
#include <hip/hip_runtime.h>

#define NN 50000
#define NE 800000
#define F_IN 128
#define HID 256
#define N_CLS 64
#define SCAN_BLOCKS ((NN + 255) / 256)   // 196
#define CROWS 515                        // basis: X,AX,A2X,A3X (4*128) + 1,d,Ad

typedef _Float16 half8 __attribute__((ext_vector_type(8)));
typedef float f32x4 __attribute__((ext_vector_type(4)));

// ================= CSR build =================
// rank[e] = position of edge e within its dst bucket (the hist atomic's old value)
__global__ void hist_count(const int* __restrict__ dst, int* __restrict__ cnt,
                           unsigned short* __restrict__ rank, int E) {
    int i = blockIdx.x * blockDim.x + threadIdx.x;
    if (i < E) rank[i] = (unsigned short)atomicAdd(&cnt[dst[i]], 1);
}

__global__ void scan_block_sums(const int* __restrict__ cnt, int* __restrict__ blockSums, int n) {
    __shared__ int s[256];
    int t = threadIdx.x;
    int i = blockIdx.x * 256 + t;
    s[t] = (i < n) ? cnt[i] : 0;
    __syncthreads();
    for (int off = 128; off > 0; off >>= 1) {
        if (t < off) s[t] += s[t + off];
        __syncthreads();
    }
    if (t == 0) blockSums[blockIdx.x] = s[0];
}

__global__ void scan_top(int* __restrict__ blockSums, int nb) {
    __shared__ int s[256];
    int t = threadIdx.x;
    s[t] = (t < nb) ? blockSums[t] : 0;
    __syncthreads();
    for (int off = 1; off < 256; off <<= 1) {
        int v = (t >= off) ? s[t - off] : 0;
        __syncthreads();
        s[t] += v;
        __syncthreads();
    }
    if (t < nb) blockSums[t] = (t > 0) ? s[t - 1] : 0;  // exclusive
}

// offs + dinv + degree-histogram (LDS-privatized), fused
__global__ void scan_final(const int* __restrict__ cnt, const int* __restrict__ blockBase,
                           int* __restrict__ offs, float* __restrict__ dinv,
                           int* __restrict__ dbin, int n) {
    __shared__ int s[256];
    __shared__ int hb[256];
    int t = threadIdx.x;
    hb[t] = 0;
    int i = blockIdx.x * 256 + t;
    int v = (i < n) ? cnt[i] : 0;
    s[t] = v;
    __syncthreads();
    for (int off = 1; off < 256; off <<= 1) {
        int u = (t >= off) ? s[t - off] : 0;
        __syncthreads();
        s[t] += u;
        __syncthreads();
    }
    if (i < n) {
        offs[i] = blockBase[blockIdx.x] + s[t] - v;
        dinv[i] = 1.0f / (float)max(v, 1);
        atomicAdd(&hb[min(v, 255)], 1);
    }
    if (i == n - 1) offs[n] = blockBase[blockIdx.x] + s[t];
    __syncthreads();
    if (hb[t]) atomicAdd(&dbin[t], hb[t]);
}

// suffix-scan of 256 degree bins -> dcur: high-degree bins get the LOWEST slots
__global__ void bin_scan(const int* __restrict__ dbin, int* __restrict__ dcur) {
    __shared__ int s[256];
    int t = threadIdx.x;
    int v0 = dbin[t];
    s[t] = v0;
    __syncthreads();
    for (int off = 1; off < 256; off <<= 1) {
        int u = (t >= off) ? s[t - off] : 0;
        __syncthreads();
        s[t] += u;
        __syncthreads();
    }
    int total = s[255];
    dcur[t] = total - s[t];   // exclusive suffix sum
}

// counting-sort placement with block-level LDS aggregation (few global atomics)
__global__ void perm_place(const int* __restrict__ cnt, int* __restrict__ dcur,
                           int* __restrict__ perm, int n) {
    __shared__ int hb[256];
    __shared__ int base[256];
    int t = threadIdx.x;
    hb[t] = 0;
    __syncthreads();
    int i = blockIdx.x * 256 + t;
    int b = -1, lr = 0;
    if (i < n) {
        b = min(cnt[i], 255);
        lr = atomicAdd(&hb[b], 1);
    }
    __syncthreads();
    if (hb[t]) base[t] = atomicAdd(&dcur[t], hb[t]);
    __syncthreads();
    if (i < n) perm[base[b] + lr] = i;
}

// atomic-free placement: slot fully determined by offs + rank
__global__ void csr_place2(const int* __restrict__ src, const int* __restrict__ dst,
                           const unsigned short* __restrict__ rank, const int* __restrict__ offs,
                           unsigned short* __restrict__ csr, int E) {
    int e = blockIdx.x * blockDim.x + threadIdx.x;
    if (e < E) csr[offs[dst[e]] + rank[e]] = (unsigned short)src[e];
}

// ================= affine-map composition =================
__device__ __forceinline__ const float* virtC1_row(int r, const float* W0s,
                                                   const float* W0n, const float* b0) {
    if (r < 0) return nullptr;
    if (r < 128) return W0s + (size_t)r * 256;
    if (r < 256) return W0n + (size_t)(r - 128) * 256;
    if (r == 512) return b0;
    return nullptr;
}

__device__ __forceinline__ int shift_src(int r) {
    if (r >= 128 && r < 512) return r - 128;
    if (r == 513) return 512;
    if (r == 514) return 513;
    return -1;
}

// layer-1 compose: C = virtC1 @ W1s + shiftA(virtC1) @ W1n ; row 512 += b1. K=M=256.
__global__ __launch_bounds__(256) void gemm_compose_first(
    const float* __restrict__ W0s, const float* __restrict__ W0n, const float* __restrict__ b0,
    const float* __restrict__ B1, const float* __restrict__ B2,
    const float* __restrict__ brow, float* __restrict__ C)
{
    __shared__ float As[64][17];
    __shared__ float Bs[16][64];
    const int tid = threadIdx.x;
    const int tx = tid & 15, ty = tid >> 4;
    const int row0 = blockIdx.x * 64;
    const int col0 = blockIdx.y * 64;
    const int lr = tid >> 2, lc = tid & 3;
    const int br = tid >> 4, bc = tid & 15;

    float acc[4][4] = {};

    for (int pass = 0; pass < 2; ++pass) {
        const float* B = pass ? B2 : B1;
        int grow = row0 + lr;
        int srcr = pass ? shift_src(grow) : (grow < CROWS ? grow : -1);
        const float* ap = virtC1_row(srcr, W0s, W0n, b0);

        for (int k0 = 0; k0 < 256; k0 += 16) {
            float4 av = make_float4(0.f, 0.f, 0.f, 0.f);
            if (ap) av = *(const float4*)(ap + k0 + lc * 4);
            As[lr][lc * 4 + 0] = av.x;
            As[lr][lc * 4 + 1] = av.y;
            As[lr][lc * 4 + 2] = av.z;
            As[lr][lc * 4 + 3] = av.w;
            *(float4*)&Bs[br][bc * 4] = *(const float4*)(B + (size_t)(k0 + br) * 256 + col0 + bc * 4);
            __syncthreads();
            #pragma unroll
            for (int k = 0; k < 16; ++k) {
                float a[4];
                #pragma unroll
                for (int i = 0; i < 4; ++i) a[i] = As[ty * 4 + i][k];
                float4 bv = *(const float4*)&Bs[k][tx * 4];
                const float b[4] = {bv.x, bv.y, bv.z, bv.w};
                #pragma unroll
                for (int i = 0; i < 4; ++i)
                    #pragma unroll
                    for (int j = 0; j < 4; ++j)
                        acc[i][j] += a[i] * b[j];
            }
            __syncthreads();
        }
    }

    #pragma unroll
    for (int i = 0; i < 4; ++i) {
        int r = row0 + ty * 4 + i;
        if (r < CROWS) {
            #pragma unroll
            for (int j = 0; j < 4; ++j) {
                float v = acc[i][j];
                if (r == 512) v += brow[col0 + tx * 4 + j];
                C[(size_t)r * 256 + col0 + tx * 4 + j] = v;
            }
        }
    }
}

// middle compose: C = A @ B1 + shiftA(A) @ B2 ; row 512 += b. K=M=256.
__global__ __launch_bounds__(256) void gemm_compose_mid(
    const float* __restrict__ A,
    const float* __restrict__ B1, const float* __restrict__ B2,
    const float* __restrict__ brow, float* __restrict__ C)
{
    __shared__ float As[64][17];
    __shared__ float Bs[16][64];
    const int tid = threadIdx.x;
    const int tx = tid & 15, ty = tid >> 4;
    const int row0 = blockIdx.x * 64;
    const int col0 = blockIdx.y * 64;
    const int lr = tid >> 2, lc = tid & 3;
    const int br = tid >> 4, bc = tid & 15;

    float acc[4][4] = {};

    for (int pass = 0; pass < 2; ++pass) {
        const float* B = pass ? B2 : B1;
        int grow = row0 + lr;
        int p = pass ? shift_src(grow) : (grow < CROWS ? grow : -1);

        for (int k0 = 0; k0 < 256; k0 += 16) {
            float4 av = make_float4(0.f, 0.f, 0.f, 0.f);
            if (p >= 0) av = *(const float4*)(A + (size_t)p * 256 + k0 + lc * 4);
            As[lr][lc * 4 + 0] = av.x;
            As[lr][lc * 4 + 1] = av.y;
            As[lr][lc * 4 + 2] = av.z;
            As[lr][lc * 4 + 3] = av.w;
            *(float4*)&Bs[br][bc * 4] = *(const float4*)(B + (size_t)(k0 + br) * 256 + col0 + bc * 4);
            __syncthreads();
            #pragma unroll
            for (int k = 0; k < 16; ++k) {
                float a[4];
                #pragma unroll
                for (int i = 0; i < 4; ++i) a[i] = As[ty * 4 + i][k];
                float4 bv = *(const float4*)&Bs[k][tx * 4];
                const float b[4] = {bv.x, bv.y, bv.z, bv.w};
                #pragma unroll
                for (int i = 0; i < 4; ++i)
                    #pragma unroll
                    for (int j = 0; j < 4; ++j)
                        acc[i][j] += a[i] * b[j];
            }
            __syncthreads();
        }
    }

    #pragma unroll
    for (int i = 0; i < 4; ++i) {
        int r = row0 + ty * 4 + i;
        if (r < CROWS) {
            #pragma unroll
            for (int j = 0; j < 4; ++j) {
                float v = acc[i][j];
                if (r == 512) v += brow[col0 + tx * 4 + j];
                C[(size_t)r * 256 + col0 + tx * 4 + j] = v;
            }
        }
    }
}

// final compose: Vf[515][64] = A @ Wfc ; row 512 += bfc. Also emits BT fp16 [256][128].
__global__ __launch_bounds__(256) void gemm_compose_last(
    const float* __restrict__ A, const float* __restrict__ B1,
    const float* __restrict__ brow, float* __restrict__ Vf, _Float16* __restrict__ BT)
{
    __shared__ float As[64][17];
    __shared__ float Bs[16][64];
    const int tid = threadIdx.x;
    const int tx = tid & 15, ty = tid >> 4;
    const int row0 = blockIdx.x * 64;
    const int lr = tid >> 2, lc = tid & 3;
    const int br = tid >> 4, bc = tid & 15;

    float acc[4][4] = {};

    for (int k0 = 0; k0 < 256; k0 += 16) {
        float4 av = make_float4(0.f, 0.f, 0.f, 0.f);
        int grow = row0 + lr;
        if (grow < CROWS) av = *(const float4*)(A + (size_t)grow * 256 + k0 + lc * 4);
        As[lr][lc * 4 + 0] = av.x;
        As[lr][lc * 4 + 1] = av.y;
        As[lr][lc * 4 + 2] = av.z;
        As[lr][lc * 4 + 3] = av.w;
        *(float4*)&Bs[br][bc * 4] = *(const float4*)(B1 + (size_t)(k0 + br) * 64 + bc * 4);
        __syncthreads();
        #pragma unroll
        for (int k = 0; k < 16; ++k) {
            float a[4];
            #pragma unroll
            for (int i = 0; i < 4; ++i) a[i] = As[ty * 4 + i][k];
            float4 bv = *(const float4*)&Bs[k][tx * 4];
            const float b[4] = {bv.x, bv.y, bv.z, bv.w};
            #pragma unroll
            for (int i = 0; i < 4; ++i)
                #pragma unroll
                for (int j = 0; j < 4; ++j)
                    acc[i][j] += a[i] * b[j];
        }
        __syncthreads();
    }

    #pragma unroll
    for (int i = 0; i < 4; ++i) {
        int r = row0 + ty * 4 + i;
        if (r < CROWS) {
            #pragma unroll
            for (int j = 0; j < 4; ++j) {
                int c = tx * 4 + j;
                float v = acc[i][j];
                if (r == 512) v += brow[c];
                Vf[(size_t)r * 64 + c] = v;
                if (r < 512)
                    BT[(size_t)((r >> 7) * 64 + c) * 128 + (r & 127)] = (_Float16)v;
            }
        }
    }
}

// ================= Y GEMM: Y[N][256] = X(fp32)[N][128] @ BT^T, fp16 out =================
__global__ __launch_bounds__(256) void gemm_Y(
    const float* __restrict__ X, const _Float16* __restrict__ BT,
    _Float16* __restrict__ Y, int N)
{
    constexpr int LP = 40;
    __shared__ _Float16 As[128 * LP];
    __shared__ _Float16 Bs[128 * LP];

    const int tid = threadIdx.x;
    const int wave = tid >> 6;
    const int lane = tid & 63;
    const int l15 = lane & 15;
    const int quad = lane >> 4;
    const int wrow = wave >> 1;
    const int wcol = wave & 1;
    const int m_base = wrow * 64;
    const int n_base = wcol * 64;

    const int row0 = blockIdx.x * 128;
    const int col0 = blockIdx.y * 128;

    f32x4 acc[4][4] = {};

    for (int k0 = 0; k0 < 128; k0 += 32) {
        #pragma unroll
        for (int r = 0; r < 2; ++r) {
            int idx = r * 256 + tid;
            int row = idx >> 2, ch = idx & 3;
            int gr = row0 + row; if (gr > N - 1) gr = N - 1;
            const float* ap = X + (size_t)gr * 128 + k0 + ch * 8;
            float4 f0 = *(const float4*)ap;
            float4 f1 = *(const float4*)(ap + 4);
            half8 v = { (_Float16)f0.x, (_Float16)f0.y, (_Float16)f0.z, (_Float16)f0.w,
                        (_Float16)f1.x, (_Float16)f1.y, (_Float16)f1.z, (_Float16)f1.w };
            *(half8*)&As[row * LP + ch * 8] = v;
        }
        #pragma unroll
        for (int r = 0; r < 2; ++r) {
            int idx = r * 256 + tid;
            int row = idx >> 2, ch = idx & 3;
            *(half8*)&Bs[row * LP + ch * 8] =
                *(const half8*)(BT + (size_t)(col0 + row) * 128 + k0 + ch * 8);
        }
        __syncthreads();
        half8 af[4], bf[4];
        #pragma unroll
        for (int i = 0; i < 4; ++i)
            af[i] = *(const half8*)&As[(m_base + i * 16 + l15) * LP + quad * 8];
        #pragma unroll
        for (int j = 0; j < 4; ++j)
            bf[j] = *(const half8*)&Bs[(n_base + j * 16 + l15) * LP + quad * 8];
        #pragma unroll
        for (int i = 0; i < 4; ++i)
            #pragma unroll
            for (int j = 0; j < 4; ++j)
                acc[i][j] = __builtin_amdgcn_mfma_f32_16x16x32_f16(af[i], bf[j], acc[i][j], 0, 0, 0);
        __syncthreads();
    }

    #pragma unroll
    for (int i = 0; i < 4; ++i) {
        #pragma unroll
        for (int j = 0; j < 4; ++j) {
            int col = col0 + n_base + j * 16 + l15;
            #pragma unroll
            for (int r = 0; r < 4; ++r) {
                int row = row0 + m_base + i * 16 + quad * 4 + r;
                if (row < N)
                    Y[(size_t)row * 256 + col] = (_Float16)acc[i][j][r];
            }
        }
    }
}

// ================= output-side gather chain (degree-sorted node order) =================
template <bool OUT_F32>
__global__ __launch_bounds__(256) void gather64(
    const _Float16* __restrict__ Tin, int sin,
    const unsigned short* __restrict__ csr, const int* __restrict__ offs,
    const int* __restrict__ perm,
    const float* __restrict__ dinv,
    const _Float16* __restrict__ Yadd,   // stride 256, pre-offset to column block
    const float* __restrict__ cvec,      // 64 floats
    void* __restrict__ Tout, int N)
{
    int slot = blockIdx.x * 32 + (threadIdx.x >> 3);
    int lane = threadIdx.x & 7;
    if (slot >= N) return;
    int node = perm[slot];
    int beg = offs[node], end = offs[node + 1];
    float acc[8] = {};
    int e = beg;
    for (; e + 3 < end; e += 4) {
        int s0 = csr[e], s1 = csr[e + 1], s2 = csr[e + 2], s3 = csr[e + 3];
        half8 v0 = *(const half8*)(Tin + (size_t)s0 * sin + lane * 8);
        half8 v1 = *(const half8*)(Tin + (size_t)s1 * sin + lane * 8);
        half8 v2 = *(const half8*)(Tin + (size_t)s2 * sin + lane * 8);
        half8 v3 = *(const half8*)(Tin + (size_t)s3 * sin + lane * 8);
        #pragma unroll
        for (int j = 0; j < 8; ++j)
            acc[j] += ((float)v0[j] + (float)v1[j]) + ((float)v2[j] + (float)v3[j]);
    }
    for (; e < end; ++e) {
        half8 v = *(const half8*)(Tin + (size_t)csr[e] * sin + lane * 8);
        #pragma unroll
        for (int j = 0; j < 8; ++j) acc[j] += (float)v[j];
    }
    float sc = dinv[node];
    half8 y = *(const half8*)(Yadd + (size_t)node * 256 + lane * 8);
    if (OUT_F32) {
        float* o = (float*)Tout + (size_t)node * 64 + lane * 8;
        float4 o0, o1;
        o0.x = acc[0] * sc + (float)y[0] + cvec[lane * 8 + 0];
        o0.y = acc[1] * sc + (float)y[1] + cvec[lane * 8 + 1];
        o0.z = acc[2] * sc + (float)y[2] + cvec[lane * 8 + 2];
        o0.w = acc[3] * sc + (float)y[3] + cvec[lane * 8 + 3];
        o1.x = acc[4] * sc + (float)y[4] + cvec[lane * 8 + 4];
        o1.y = acc[5] * sc + (float)y[5] + cvec[lane * 8 + 5];
        o1.z = acc[6] * sc + (float)y[6] + cvec[lane * 8 + 6];
        o1.w = acc[7] * sc + (float)y[7] + cvec[lane * 8 + 7];
        *(float4*)o = o0;
        *(float4*)(o + 4) = o1;
    } else {
        half8 o;
        #pragma unroll
        for (int j = 0; j < 8; ++j)
            o[j] = (_Float16)(acc[j] * sc + (float)y[j] + cvec[lane * 8 + j]);
        *(half8*)((_Float16*)Tout + (size_t)node * 64 + lane * 8) = o;
    }
}

extern "C" void kernel_launch(void* const* d_in, const int* in_sizes, int n_in,
                              void* d_out, int out_size, void* d_ws, size_t ws_size,
                              hipStream_t stream) {
    const float* x    = (const float*)d_in[0];
    const int*   esrc = (const int*)d_in[1];
    const int*   edst = (const int*)d_in[2];
    const float* W0s  = (const float*)d_in[3];
    const float* W0n  = (const float*)d_in[4];
    const float* b0   = (const float*)d_in[5];
    const float* W1s  = (const float*)d_in[6];
    const float* W1n  = (const float*)d_in[7];
    const float* b1   = (const float*)d_in[8];
    const float* W2s  = (const float*)d_in[9];
    const float* W2n  = (const float*)d_in[10];
    const float* b2   = (const float*)d_in[11];
    const float* Wfc  = (const float*)d_in[12];
    const float* bfc  = (const float*)d_in[13];
    float* out = (float*)d_out;

    // ---- workspace layout ----
    _Float16* Y   = (_Float16*)d_ws;                  // N x 256  [Y0|Y1|Y2|Y3]
    _Float16* Ta  = Y + (size_t)NN * 256;             // N x 64
    _Float16* Tb  = Ta + (size_t)NN * 64;             // N x 64
    _Float16* BT  = Tb + (size_t)NN * 64;             // 256 x 128
    float* C2     = (float*)(BT + 256 * 128);         // 515 x 256
    float* C3     = C2 + CROWS * 256;                 // 515 x 256
    float* Vf     = C3 + CROWS * 256;                 // 515 x 64
    float* dinv   = Vf + CROWS * 64;                  // N
    int* cnt      = (int*)(dinv + NN);                // N      (memset block start)
    int* dbin     = cnt + NN;                         // 256
    int* dcur     = dbin + 256;                       // 256    (memset block end)
    int* offs     = dcur + 256;                       // N+1
    int* perm     = offs + NN + 1;                    // N
    int* blockSums = perm + NN;                       // SCAN_BLOCKS
    unsigned short* rank = (unsigned short*)(blockSums + SCAN_BLOCKS);  // E
    unsigned short* csr  = rank + NE;                 // E

    // ---- CSR build + degree sort ----
    hipMemsetAsync(cnt, 0, (size_t)(NN + 512) * sizeof(int), stream);  // cnt + dbin + dcur
    hist_count<<<(NE + 255) / 256, 256, 0, stream>>>(edst, cnt, rank, NE);
    scan_block_sums<<<SCAN_BLOCKS, 256, 0, stream>>>(cnt, blockSums, NN);
    scan_top<<<1, 256, 0, stream>>>(blockSums, SCAN_BLOCKS);
    scan_final<<<SCAN_BLOCKS, 256, 0, stream>>>(cnt, blockSums, offs, dinv, dbin, NN);
    bin_scan<<<1, 256, 0, stream>>>(dbin, dcur);
    perm_place<<<SCAN_BLOCKS, 256, 0, stream>>>(cnt, dcur, perm, NN);
    csr_place2<<<(NE + 255) / 256, 256, 0, stream>>>(esrc, edst, rank, offs, csr, NE);

    // ---- weight-chain composition (fp32) ----
    const int gR = (CROWS + 63) / 64;   // 9
    gemm_compose_first<<<dim3(gR, 4), 256, 0, stream>>>(W0s, W0n, b0, W1s, W1n, b1, C2);
    gemm_compose_mid<<<dim3(gR, 4), 256, 0, stream>>>(C2, W2s, W2n, b2, C3);
    gemm_compose_last<<<dim3(gR, 1), 256, 0, stream>>>(C3, Wfc, bfc, Vf, BT);

    // ---- Y = X @ [V0|V1|V2|V3] ----
    gemm_Y<<<dim3((NN + 127) / 128, 2), 256, 0, stream>>>(x, BT, Y, NN);

    // ---- output-side propagation: out = Y0 + c1 + A(Y1 + c2 + A(Y2 + c3 + A*Y3)) ----
    const int ggrid = (NN + 31) / 32;
    gather64<false><<<ggrid, 256, 0, stream>>>(
        Y + 192, 256, csr, offs, perm, dinv, Y + 128, Vf + (size_t)514 * 64, Ta, NN);
    gather64<false><<<ggrid, 256, 0, stream>>>(
        Ta, 64, csr, offs, perm, dinv, Y + 64, Vf + (size_t)513 * 64, Tb, NN);
    gather64<true><<<ggrid, 256, 0, stream>>>(
        Tb, 64, csr, offs, perm, dinv, Y, Vf + (size_t)512 * 64, out, NN);
}

// Round 8
// 291.327 us; speedup vs baseline: 1.0607x; 1.0607x over previous
//
#include <hip/hip_runtime.h>

#define NN 50000
#define NE 800000
#define F_IN 128
#define HID 256
#define N_CLS 64
#define SCAN_BLOCKS ((NN + 255) / 256)   // 196
#define CROWS 515                        // basis: X,AX,A2X,A3X (4*128) + 1,d,Ad

typedef _Float16 half8 __attribute__((ext_vector_type(8)));
typedef float f32x4 __attribute__((ext_vector_type(4)));

// ================= CSR build =================
__global__ void hist_count(const int* __restrict__ dst, int* __restrict__ cnt,
                           unsigned short* __restrict__ rank, int E) {
    int i = blockIdx.x * blockDim.x + threadIdx.x;
    if (i < E) rank[i] = (unsigned short)atomicAdd(&cnt[dst[i]], 1);
}

__device__ __forceinline__ void scan_block_sums_dev(const int* __restrict__ cnt,
                                                    int* __restrict__ blockSums, int n) {
    __shared__ int s[256];
    int t = threadIdx.x;
    int i = blockIdx.x * 256 + t;
    s[t] = (i < n) ? cnt[i] : 0;
    __syncthreads();
    for (int off = 128; off > 0; off >>= 1) {
        if (t < off) s[t] += s[t + off];
        __syncthreads();
    }
    if (t == 0) blockSums[blockIdx.x] = s[0];
}

__device__ __forceinline__ void scan_top_dev(int* __restrict__ blockSums, int nb) {
    __shared__ int s[256];
    int t = threadIdx.x;
    s[t] = (t < nb) ? blockSums[t] : 0;
    __syncthreads();
    for (int off = 1; off < 256; off <<= 1) {
        int v = (t >= off) ? s[t - off] : 0;
        __syncthreads();
        s[t] += v;
        __syncthreads();
    }
    if (t < nb) blockSums[t] = (t > 0) ? s[t - 1] : 0;  // exclusive
}

__device__ __forceinline__ void scan_final_dev(const int* __restrict__ cnt,
                                               const int* __restrict__ blockBase,
                                               int* __restrict__ offs,
                                               float* __restrict__ dinv, int n) {
    __shared__ int s[256];
    int t = threadIdx.x;
    int i = blockIdx.x * 256 + t;
    int v = (i < n) ? cnt[i] : 0;
    s[t] = v;
    __syncthreads();
    for (int off = 1; off < 256; off <<= 1) {
        int u = (t >= off) ? s[t - off] : 0;
        __syncthreads();
        s[t] += u;
        __syncthreads();
    }
    if (i < n) {
        offs[i] = blockBase[blockIdx.x] + s[t] - v;
        dinv[i] = 1.0f / (float)max(v, 1);
    }
    if (i == n - 1) offs[n] = blockBase[blockIdx.x] + s[t];
}

__global__ void csr_place2(const int* __restrict__ src, const int* __restrict__ dst,
                           const unsigned short* __restrict__ rank, const int* __restrict__ offs,
                           unsigned short* __restrict__ csr, int E) {
    int e = blockIdx.x * blockDim.x + threadIdx.x;
    if (e < E) csr[offs[dst[e]] + rank[e]] = (unsigned short)src[e];
}

// ================= affine-map composition =================
__device__ __forceinline__ const float* virtC1_row(int r, const float* W0s,
                                                   const float* W0n, const float* b0) {
    if (r < 0) return nullptr;
    if (r < 128) return W0s + (size_t)r * 256;
    if (r < 256) return W0n + (size_t)(r - 128) * 256;
    if (r == 512) return b0;
    return nullptr;
}

__device__ __forceinline__ int shift_src(int r) {
    if (r >= 128 && r < 512) return r - 128;
    if (r == 513) return 512;
    if (r == 514) return 513;
    return -1;
}

// shared inner: acc += As-tile (already staged per-pass by caller) -- full body kept inline below

__device__ __forceinline__ void compose_first_dev(
    int bx, const float* __restrict__ W0s, const float* __restrict__ W0n,
    const float* __restrict__ b0,
    const float* __restrict__ B1, const float* __restrict__ B2,
    const float* __restrict__ brow, float* __restrict__ C)
{
    __shared__ float As[64][17];
    __shared__ float Bs[16][64];
    const int tid = threadIdx.x;
    const int tx = tid & 15, ty = tid >> 4;
    const int row0 = (bx % 9) * 64;
    const int col0 = (bx / 9) * 64;
    const int lr = tid >> 2, lc = tid & 3;
    const int br = tid >> 4, bc = tid & 15;

    float acc[4][4] = {};

    for (int pass = 0; pass < 2; ++pass) {
        const float* B = pass ? B2 : B1;
        int grow = row0 + lr;
        int srcr = pass ? shift_src(grow) : (grow < CROWS ? grow : -1);
        const float* ap = virtC1_row(srcr, W0s, W0n, b0);

        for (int k0 = 0; k0 < 256; k0 += 16) {
            float4 av = make_float4(0.f, 0.f, 0.f, 0.f);
            if (ap) av = *(const float4*)(ap + k0 + lc * 4);
            As[lr][lc * 4 + 0] = av.x;
            As[lr][lc * 4 + 1] = av.y;
            As[lr][lc * 4 + 2] = av.z;
            As[lr][lc * 4 + 3] = av.w;
            *(float4*)&Bs[br][bc * 4] = *(const float4*)(B + (size_t)(k0 + br) * 256 + col0 + bc * 4);
            __syncthreads();
            #pragma unroll
            for (int k = 0; k < 16; ++k) {
                float a[4];
                #pragma unroll
                for (int i = 0; i < 4; ++i) a[i] = As[ty * 4 + i][k];
                float4 bv = *(const float4*)&Bs[k][tx * 4];
                const float b[4] = {bv.x, bv.y, bv.z, bv.w};
                #pragma unroll
                for (int i = 0; i < 4; ++i)
                    #pragma unroll
                    for (int j = 0; j < 4; ++j)
                        acc[i][j] += a[i] * b[j];
            }
            __syncthreads();
        }
    }

    #pragma unroll
    for (int i = 0; i < 4; ++i) {
        int r = row0 + ty * 4 + i;
        if (r < CROWS) {
            #pragma unroll
            for (int j = 0; j < 4; ++j) {
                float v = acc[i][j];
                if (r == 512) v += brow[col0 + tx * 4 + j];
                C[(size_t)r * 256 + col0 + tx * 4 + j] = v;
            }
        }
    }
}

__device__ __forceinline__ void compose_mid_dev(
    int bx, const float* __restrict__ A,
    const float* __restrict__ B1, const float* __restrict__ B2,
    const float* __restrict__ brow, float* __restrict__ C)
{
    __shared__ float As[64][17];
    __shared__ float Bs[16][64];
    const int tid = threadIdx.x;
    const int tx = tid & 15, ty = tid >> 4;
    const int row0 = (bx % 9) * 64;
    const int col0 = (bx / 9) * 64;
    const int lr = tid >> 2, lc = tid & 3;
    const int br = tid >> 4, bc = tid & 15;

    float acc[4][4] = {};

    for (int pass = 0; pass < 2; ++pass) {
        const float* B = pass ? B2 : B1;
        int grow = row0 + lr;
        int p = pass ? shift_src(grow) : (grow < CROWS ? grow : -1);

        for (int k0 = 0; k0 < 256; k0 += 16) {
            float4 av = make_float4(0.f, 0.f, 0.f, 0.f);
            if (p >= 0) av = *(const float4*)(A + (size_t)p * 256 + k0 + lc * 4);
            As[lr][lc * 4 + 0] = av.x;
            As[lr][lc * 4 + 1] = av.y;
            As[lr][lc * 4 + 2] = av.z;
            As[lr][lc * 4 + 3] = av.w;
            *(float4*)&Bs[br][bc * 4] = *(const float4*)(B + (size_t)(k0 + br) * 256 + col0 + bc * 4);
            __syncthreads();
            #pragma unroll
            for (int k = 0; k < 16; ++k) {
                float a[4];
                #pragma unroll
                for (int i = 0; i < 4; ++i) a[i] = As[ty * 4 + i][k];
                float4 bv = *(const float4*)&Bs[k][tx * 4];
                const float b[4] = {bv.x, bv.y, bv.z, bv.w};
                #pragma unroll
                for (int i = 0; i < 4; ++i)
                    #pragma unroll
                    for (int j = 0; j < 4; ++j)
                        acc[i][j] += a[i] * b[j];
            }
            __syncthreads();
        }
    }

    #pragma unroll
    for (int i = 0; i < 4; ++i) {
        int r = row0 + ty * 4 + i;
        if (r < CROWS) {
            #pragma unroll
            for (int j = 0; j < 4; ++j) {
                float v = acc[i][j];
                if (r == 512) v += brow[col0 + tx * 4 + j];
                C[(size_t)r * 256 + col0 + tx * 4 + j] = v;
            }
        }
    }
}

__device__ __forceinline__ void compose_last_dev(
    int bx, const float* __restrict__ A, const float* __restrict__ B1,
    const float* __restrict__ brow, float* __restrict__ Vf, _Float16* __restrict__ BT)
{
    __shared__ float As[64][17];
    __shared__ float Bs[16][64];
    const int tid = threadIdx.x;
    const int tx = tid & 15, ty = tid >> 4;
    const int row0 = bx * 64;
    const int lr = tid >> 2, lc = tid & 3;
    const int br = tid >> 4, bc = tid & 15;

    float acc[4][4] = {};

    for (int k0 = 0; k0 < 256; k0 += 16) {
        float4 av = make_float4(0.f, 0.f, 0.f, 0.f);
        int grow = row0 + lr;
        if (grow < CROWS) av = *(const float4*)(A + (size_t)grow * 256 + k0 + lc * 4);
        As[lr][lc * 4 + 0] = av.x;
        As[lr][lc * 4 + 1] = av.y;
        As[lr][lc * 4 + 2] = av.z;
        As[lr][lc * 4 + 3] = av.w;
        *(float4*)&Bs[br][bc * 4] = *(const float4*)(B1 + (size_t)(k0 + br) * 64 + bc * 4);
        __syncthreads();
        #pragma unroll
        for (int k = 0; k < 16; ++k) {
            float a[4];
            #pragma unroll
            for (int i = 0; i < 4; ++i) a[i] = As[ty * 4 + i][k];
            float4 bv = *(const float4*)&Bs[k][tx * 4];
            const float b[4] = {bv.x, bv.y, bv.z, bv.w};
            #pragma unroll
            for (int i = 0; i < 4; ++i)
                #pragma unroll
                for (int j = 0; j < 4; ++j)
                    acc[i][j] += a[i] * b[j];
        }
        __syncthreads();
    }

    #pragma unroll
    for (int i = 0; i < 4; ++i) {
        int r = row0 + ty * 4 + i;
        if (r < CROWS) {
            #pragma unroll
            for (int j = 0; j < 4; ++j) {
                int c = tx * 4 + j;
                float v = acc[i][j];
                if (r == 512) v += brow[c];
                Vf[(size_t)r * 64 + c] = v;
                if (r < 512)
                    BT[(size_t)((r >> 7) * 64 + c) * 128 + (r & 127)] = (_Float16)v;
            }
        }
    }
}

// ============ packed kernels: scan chain + compose chain ride together ============
__global__ __launch_bounds__(256) void k_scanA_composeF(
    const int* __restrict__ cnt, int* __restrict__ blockSums,
    const float* __restrict__ W0s, const float* __restrict__ W0n, const float* __restrict__ b0,
    const float* __restrict__ W1s, const float* __restrict__ W1n, const float* __restrict__ b1,
    float* __restrict__ C2)
{
    if (blockIdx.x < SCAN_BLOCKS) scan_block_sums_dev(cnt, blockSums, NN);
    else compose_first_dev(blockIdx.x - SCAN_BLOCKS, W0s, W0n, b0, W1s, W1n, b1, C2);
}

__global__ __launch_bounds__(256) void k_scanT_composeM(
    int* __restrict__ blockSums,
    const float* __restrict__ C2,
    const float* __restrict__ W2s, const float* __restrict__ W2n, const float* __restrict__ b2,
    float* __restrict__ C3)
{
    if (blockIdx.x == 0) scan_top_dev(blockSums, SCAN_BLOCKS);
    else compose_mid_dev(blockIdx.x - 1, C2, W2s, W2n, b2, C3);
}

__global__ __launch_bounds__(256) void k_scanF_composeL(
    const int* __restrict__ cnt, const int* __restrict__ blockBase,
    int* __restrict__ offs, float* __restrict__ dinv,
    const float* __restrict__ C3, const float* __restrict__ Wfc, const float* __restrict__ bfc,
    float* __restrict__ Vf, _Float16* __restrict__ BT)
{
    if (blockIdx.x < SCAN_BLOCKS) scan_final_dev(cnt, blockBase, offs, dinv, NN);
    else compose_last_dev(blockIdx.x - SCAN_BLOCKS, C3, Wfc, bfc, Vf, BT);
}

// ================= Y GEMM: Y[N][256] = X(fp32)[N][128] @ BT^T, fp16 out ===========
// also writes cols 192..255 (the Y3 block) densely into Tc[N][64]
__global__ __launch_bounds__(256) void gemm_Y(
    const float* __restrict__ X, const _Float16* __restrict__ BT,
    _Float16* __restrict__ Y, _Float16* __restrict__ Tc, int N)
{
    constexpr int LP = 40;
    __shared__ _Float16 As[128 * LP];
    __shared__ _Float16 Bs[128 * LP];

    const int tid = threadIdx.x;
    const int wave = tid >> 6;
    const int lane = tid & 63;
    const int l15 = lane & 15;
    const int quad = lane >> 4;
    const int wrow = wave >> 1;
    const int wcol = wave & 1;
    const int m_base = wrow * 64;
    const int n_base = wcol * 64;

    const int row0 = blockIdx.x * 128;
    const int col0 = blockIdx.y * 128;

    f32x4 acc[4][4] = {};

    for (int k0 = 0; k0 < 128; k0 += 32) {
        #pragma unroll
        for (int r = 0; r < 2; ++r) {
            int idx = r * 256 + tid;
            int row = idx >> 2, ch = idx & 3;
            int gr = row0 + row; if (gr > N - 1) gr = N - 1;
            const float* ap = X + (size_t)gr * 128 + k0 + ch * 8;
            float4 f0 = *(const float4*)ap;
            float4 f1 = *(const float4*)(ap + 4);
            half8 v = { (_Float16)f0.x, (_Float16)f0.y, (_Float16)f0.z, (_Float16)f0.w,
                        (_Float16)f1.x, (_Float16)f1.y, (_Float16)f1.z, (_Float16)f1.w };
            *(half8*)&As[row * LP + ch * 8] = v;
        }
        #pragma unroll
        for (int r = 0; r < 2; ++r) {
            int idx = r * 256 + tid;
            int row = idx >> 2, ch = idx & 3;
            *(half8*)&Bs[row * LP + ch * 8] =
                *(const half8*)(BT + (size_t)(col0 + row) * 128 + k0 + ch * 8);
        }
        __syncthreads();
        half8 af[4], bf[4];
        #pragma unroll
        for (int i = 0; i < 4; ++i)
            af[i] = *(const half8*)&As[(m_base + i * 16 + l15) * LP + quad * 8];
        #pragma unroll
        for (int j = 0; j < 4; ++j)
            bf[j] = *(const half8*)&Bs[(n_base + j * 16 + l15) * LP + quad * 8];
        #pragma unroll
        for (int i = 0; i < 4; ++i)
            #pragma unroll
            for (int j = 0; j < 4; ++j)
                acc[i][j] = __builtin_amdgcn_mfma_f32_16x16x32_f16(af[i], bf[j], acc[i][j], 0, 0, 0);
        __syncthreads();
    }

    #pragma unroll
    for (int i = 0; i < 4; ++i) {
        #pragma unroll
        for (int j = 0; j < 4; ++j) {
            int col = col0 + n_base + j * 16 + l15;
            #pragma unroll
            for (int r = 0; r < 4; ++r) {
                int row = row0 + m_base + i * 16 + quad * 4 + r;
                if (row < N) {
                    _Float16 v = (_Float16)acc[i][j][r];
                    Y[(size_t)row * 256 + col] = v;
                    if (col >= 192) Tc[(size_t)row * 64 + (col - 192)] = v;
                }
            }
        }
    }
}

// ================= output-side gather chain =================
template <bool OUT_F32>
__global__ __launch_bounds__(256) void gather64(
    const _Float16* __restrict__ Tin,       // stride-64 compact rows
    const unsigned short* __restrict__ csr, const int* __restrict__ offs,
    const float* __restrict__ dinv,
    const _Float16* __restrict__ Yadd,      // stride 256, pre-offset to column block
    const float* __restrict__ cvec,         // 64 floats
    void* __restrict__ Tout, int N)
{
    int node = blockIdx.x * 32 + (threadIdx.x >> 3);
    int lane = threadIdx.x & 7;
    if (node >= N) return;
    int beg = offs[node], end = offs[node + 1];
    float acc[8] = {};
    int e = beg;
    for (; e + 3 < end; e += 4) {
        int s0 = csr[e], s1 = csr[e + 1], s2 = csr[e + 2], s3 = csr[e + 3];
        half8 v0 = *(const half8*)(Tin + (size_t)s0 * 64 + lane * 8);
        half8 v1 = *(const half8*)(Tin + (size_t)s1 * 64 + lane * 8);
        half8 v2 = *(const half8*)(Tin + (size_t)s2 * 64 + lane * 8);
        half8 v3 = *(const half8*)(Tin + (size_t)s3 * 64 + lane * 8);
        #pragma unroll
        for (int j = 0; j < 8; ++j)
            acc[j] += ((float)v0[j] + (float)v1[j]) + ((float)v2[j] + (float)v3[j]);
    }
    for (; e < end; ++e) {
        half8 v = *(const half8*)(Tin + (size_t)csr[e] * 64 + lane * 8);
        #pragma unroll
        for (int j = 0; j < 8; ++j) acc[j] += (float)v[j];
    }
    float sc = dinv[node];
    half8 y = *(const half8*)(Yadd + (size_t)node * 256 + lane * 8);
    if (OUT_F32) {
        float* o = (float*)Tout + (size_t)node * 64 + lane * 8;
        float4 o0, o1;
        o0.x = acc[0] * sc + (float)y[0] + cvec[lane * 8 + 0];
        o0.y = acc[1] * sc + (float)y[1] + cvec[lane * 8 + 1];
        o0.z = acc[2] * sc + (float)y[2] + cvec[lane * 8 + 2];
        o0.w = acc[3] * sc + (float)y[3] + cvec[lane * 8 + 3];
        o1.x = acc[4] * sc + (float)y[4] + cvec[lane * 8 + 4];
        o1.y = acc[5] * sc + (float)y[5] + cvec[lane * 8 + 5];
        o1.z = acc[6] * sc + (float)y[6] + cvec[lane * 8 + 6];
        o1.w = acc[7] * sc + (float)y[7] + cvec[lane * 8 + 7];
        *(float4*)o = o0;
        *(float4*)(o + 4) = o1;
    } else {
        half8 o;
        #pragma unroll
        for (int j = 0; j < 8; ++j)
            o[j] = (_Float16)(acc[j] * sc + (float)y[j] + cvec[lane * 8 + j]);
        *(half8*)((_Float16*)Tout + (size_t)node * 64 + lane * 8) = o;
    }
}

extern "C" void kernel_launch(void* const* d_in, const int* in_sizes, int n_in,
                              void* d_out, int out_size, void* d_ws, size_t ws_size,
                              hipStream_t stream) {
    const float* x    = (const float*)d_in[0];
    const int*   esrc = (const int*)d_in[1];
    const int*   edst = (const int*)d_in[2];
    const float* W0s  = (const float*)d_in[3];
    const float* W0n  = (const float*)d_in[4];
    const float* b0   = (const float*)d_in[5];
    const float* W1s  = (const float*)d_in[6];
    const float* W1n  = (const float*)d_in[7];
    const float* b1   = (const float*)d_in[8];
    const float* W2s  = (const float*)d_in[9];
    const float* W2n  = (const float*)d_in[10];
    const float* b2   = (const float*)d_in[11];
    const float* Wfc  = (const float*)d_in[12];
    const float* bfc  = (const float*)d_in[13];
    float* out = (float*)d_out;

    // ---- workspace layout ----
    _Float16* Y   = (_Float16*)d_ws;                  // N x 256  [Y0|Y1|Y2|Y3]
    _Float16* Ta  = Y + (size_t)NN * 256;             // N x 64
    _Float16* Tb  = Ta + (size_t)NN * 64;             // N x 64
    _Float16* Tc  = Tb + (size_t)NN * 64;             // N x 64 (dense Y3 copy)
    _Float16* BT  = Tc + (size_t)NN * 64;             // 256 x 128
    float* C2     = (float*)(BT + 256 * 128);         // 515 x 256
    float* C3     = C2 + CROWS * 256;                 // 515 x 256
    float* Vf     = C3 + CROWS * 256;                 // 515 x 64
    float* dinv   = Vf + CROWS * 64;                  // N
    int* cnt      = (int*)(dinv + NN);                // N   (memset target)
    int* offs     = cnt + NN;                         // N+1
    int* blockSums = offs + NN + 1;                   // SCAN_BLOCKS
    unsigned short* rank = (unsigned short*)(blockSums + SCAN_BLOCKS);  // E
    unsigned short* csr  = rank + NE;                 // E

    // ---- CSR build interleaved with weight-chain composition ----
    hipMemsetAsync(cnt, 0, (size_t)NN * sizeof(int), stream);
    hist_count<<<(NE + 255) / 256, 256, 0, stream>>>(edst, cnt, rank, NE);
    k_scanA_composeF<<<SCAN_BLOCKS + 36, 256, 0, stream>>>(
        cnt, blockSums, W0s, W0n, b0, W1s, W1n, b1, C2);
    k_scanT_composeM<<<1 + 36, 256, 0, stream>>>(blockSums, C2, W2s, W2n, b2, C3);
    k_scanF_composeL<<<SCAN_BLOCKS + 9, 256, 0, stream>>>(
        cnt, blockSums, offs, dinv, C3, Wfc, bfc, Vf, BT);
    csr_place2<<<(NE + 255) / 256, 256, 0, stream>>>(esrc, edst, rank, offs, csr, NE);

    // ---- Y = X @ [V0|V1|V2|V3] (+ dense Y3 copy into Tc) ----
    gemm_Y<<<dim3((NN + 127) / 128, 2), 256, 0, stream>>>(x, BT, Y, Tc, NN);

    // ---- output-side propagation: out = Y0 + c1 + A(Y1 + c2 + A(Y2 + c3 + A*Y3)) ----
    const int ggrid = (NN + 31) / 32;
    gather64<false><<<ggrid, 256, 0, stream>>>(
        Tc, csr, offs, dinv, Y + 128, Vf + (size_t)514 * 64, Ta, NN);
    gather64<false><<<ggrid, 256, 0, stream>>>(
        Ta, csr, offs, dinv, Y + 64, Vf + (size_t)513 * 64, Tb, NN);
    gather64<true><<<ggrid, 256, 0, stream>>>(
        Tb, csr, offs, dinv, Y, Vf + (size_t)512 * 64, out, NN);
}